// Round 6
// baseline (947.838 us; speedup 1.0000x reference)
//
#include <hip/hip_runtime.h>
#include <hip/hip_bf16.h>

// MHA: x[4,2048,1024] fp32, 16 heads x 64, no 1/sqrt(d) scale.
// cvt(x) + cvt(4 weights, Wq*log2e) + bias-concat -> fused QKV gemm (N=3072,
// V-blocks transposed in epilogue) -> flash attention (512-thr blocks, 256-row
// q-tiles, S^T trick, raw v_exp_f32, LDS-double-buffered async K/V staging,
// one barrier/iter) -> proj gemm (fp32).

typedef short short8 __attribute__((ext_vector_type(8)));
typedef float float4v __attribute__((ext_vector_type(4)));

#define MFMA16(a, b, c) __builtin_amdgcn_mfma_f32_16x16x32_bf16((a), (b), (c), 0, 0, 0)
#define LOG2E 1.4426950408889634f

#define B_SZ 4
#define T_SZ 2048
#define D_SZ 1024
#define NH 16
#define HD 64
#define M_SZ (B_SZ * T_SZ)  // 8192

__device__ __forceinline__ unsigned short f2bf(float f) {
  unsigned int u = __float_as_uint(f);
  u += 0x7fffu + ((u >> 16) & 1u);
  return (unsigned short)(u >> 16);
}

__device__ __forceinline__ float fexp2(float x) {
#if __has_builtin(__builtin_amdgcn_exp2f)
  return __builtin_amdgcn_exp2f(x);  // bare v_exp_f32
#else
  return exp2f(x);
#endif
}

__device__ __forceinline__ void gl_lds16(const unsigned short* g, unsigned short* l) {
  __builtin_amdgcn_global_load_lds(
      (const __attribute__((address_space(1))) unsigned int*)g,
      (__attribute__((address_space(3))) unsigned int*)l, 16, 0, 0);
}

// ---------------- fp32 -> bf16 converts ----------------
__global__ __launch_bounds__(256) void cvt_kernel(const float* __restrict__ in,
                                                  unsigned short* __restrict__ out,
                                                  float scale, long n) {
  long i = ((long)blockIdx.x * 256 + threadIdx.x) * 4;
  if (i >= n) return;
  float4 v = *(const float4*)(in + i);
  uint2 o;
  o.x = (unsigned)f2bf(v.x * scale) | ((unsigned)f2bf(v.y * scale) << 16);
  o.y = (unsigned)f2bf(v.z * scale) | ((unsigned)f2bf(v.w * scale) << 16);
  *(uint2*)(out + i) = o;
}

__global__ __launch_bounds__(256) void cvt_w(const float* __restrict__ w0,
                                             const float* __restrict__ w1,
                                             const float* __restrict__ w2,
                                             const float* __restrict__ w3,
                                             unsigned short* __restrict__ out, long per) {
  long i = ((long)blockIdx.x * 256 + threadIdx.x) * 4;
  int which = (int)(i / per);
  const float* src = which == 0 ? w0 : which == 1 ? w1 : which == 2 ? w2 : w3;
  float scale = which == 0 ? LOG2E : 1.0f;
  long j = i - (long)which * per;
  float4 v = *(const float4*)(src + j);
  uint2 o;
  o.x = (unsigned)f2bf(v.x * scale) | ((unsigned)f2bf(v.y * scale) << 16);
  o.y = (unsigned)f2bf(v.z * scale) | ((unsigned)f2bf(v.w * scale) << 16);
  *(uint2*)(out + i) = o;
}

__global__ __launch_bounds__(256) void cvt_bias(const float* __restrict__ b0,
                                                const float* __restrict__ b1,
                                                const float* __restrict__ b2,
                                                float* __restrict__ out) {
  int i = blockIdx.x * 256 + threadIdx.x;  // 0..3071
  float v;
  if (i < 1024) v = b0[i] * LOG2E;
  else if (i < 2048) v = b1[i - 1024];
  else v = b2[i - 2048];
  out[i] = v;
}

// ---------------- fused QKV gemm: C[8192,3072] = x . [Wq;Wk;Wv]^T + b ----------------
__global__ __launch_bounds__(256, 2) void gemm_qkv(const unsigned short* __restrict__ A,
                                                   const unsigned short* __restrict__ W,
                                                   const float* __restrict__ bias,
                                                   unsigned short* __restrict__ Qb,
                                                   unsigned short* __restrict__ Kb,
                                                   unsigned short* __restrict__ Vt) {
  __shared__ __align__(16) unsigned short smem[17408];  // As|Bs / Ct (128x136)
  unsigned short* As = smem;
  unsigned short* Bs = smem + 8192;
  unsigned short* Ct = smem;
  const int tid = threadIdx.x;
  const int wave = tid >> 6, lane = tid & 63;
  const int q = lane >> 4, ln = lane & 15;
  const int wm = (wave >> 1) * 64, wn = (wave & 1) * 64;
  const long m0 = (long)blockIdx.y * 128;
  const long n0 = (long)blockIdx.x * 128;
  const int srow = lane >> 3, scol = (lane & 7) * 8;
  const int K = D_SZ;

  float4v acc[4][4] = {};

  for (int k0 = 0; k0 < K; k0 += 64) {
    for (int t = 0; t < 4; ++t) {
      int seg = wave * 4 + t;
      int row = seg * 8 + srow;
      gl_lds16(A + (m0 + row) * (long)K + k0 + scol, As + seg * 512);
      gl_lds16(W + (n0 + row) * (long)K + k0 + scol, Bs + seg * 512);
    }
    __syncthreads();
    for (int ks = 0; ks < 2; ++ks) {
      short8 af[4], bf[4];
      for (int i = 0; i < 4; ++i)
        af[i] = *(const short8*)(As + (wm + i * 16 + ln) * 64 + ks * 32 + q * 8);
      for (int j = 0; j < 4; ++j)
        bf[j] = *(const short8*)(Bs + (wn + j * 16 + ln) * 64 + ks * 32 + q * 8);
      for (int i = 0; i < 4; ++i)
        for (int j = 0; j < 4; ++j)
          acc[i][j] = MFMA16(af[i], bf[j], acc[i][j]);
    }
    __syncthreads();
  }

  if ((int)n0 < 2048) {
    unsigned short* dst = (int)n0 < 1024 ? Qb : Kb;
    int coff = (int)n0 < 1024 ? 0 : 1024;
    for (int i = 0; i < 4; ++i) {
      long rowb = m0 + wm + i * 16 + q * 4;
      for (int j = 0; j < 4; ++j) {
        long col = n0 + wn + j * 16 + ln;
        float bv = bias[col];
        for (int r = 0; r < 4; ++r)
          dst[(rowb + r) * (long)D_SZ + col - coff] = f2bf(acc[i][j][r] + bv);
      }
    }
  } else {
    for (int i = 0; i < 4; ++i)
      for (int j = 0; j < 4; ++j) {
        int col_l = wn + j * 16 + ln;
        float bv = bias[n0 + col_l];
        __hip_bfloat162 lo =
            __float22bfloat162_rn(make_float2(acc[i][j][0] + bv, acc[i][j][1] + bv));
        __hip_bfloat162 hi =
            __float22bfloat162_rn(make_float2(acc[i][j][2] + bv, acc[i][j][3] + bv));
        uint2 w;
        w.x = *(unsigned*)&lo;
        w.y = *(unsigned*)&hi;
        *(uint2*)(Ct + col_l * 136 + wm + i * 16 + q * 4) = w;
      }
    __syncthreads();
    for (int it = 0; it < 8; ++it) {
      int idx = tid + it * 256;
      int c = idx >> 4, rb = idx & 15;
      uint4 v = *(const uint4*)(Ct + c * 136 + rb * 8);
      *(uint4*)(Vt + (n0 - 2048 + c) * (long)M_SZ + m0 + rb * 8) = v;
    }
  }
}

// ---------------- proj gemm: out[8192,1024] = Ob . Wp^T + bp (fp32) ----------------
__global__ __launch_bounds__(256, 2) void gemm_proj(const unsigned short* __restrict__ A,
                                                    const unsigned short* __restrict__ W,
                                                    const float* __restrict__ bias,
                                                    float* __restrict__ Cf) {
  __shared__ __align__(16) unsigned short As[128 * 64];
  __shared__ __align__(16) unsigned short Bs[128 * 64];
  const int tid = threadIdx.x;
  const int wave = tid >> 6, lane = tid & 63;
  const int q = lane >> 4, ln = lane & 15;
  const int wm = (wave >> 1) * 64, wn = (wave & 1) * 64;
  const long m0 = (long)blockIdx.y * 128;
  const long n0 = (long)blockIdx.x * 128;
  const int srow = lane >> 3, scol = (lane & 7) * 8;
  const int K = D_SZ;

  float4v acc[4][4] = {};
  for (int k0 = 0; k0 < K; k0 += 64) {
    for (int t = 0; t < 4; ++t) {
      int seg = wave * 4 + t;
      int row = seg * 8 + srow;
      gl_lds16(A + (m0 + row) * (long)K + k0 + scol, As + seg * 512);
      gl_lds16(W + (n0 + row) * (long)K + k0 + scol, Bs + seg * 512);
    }
    __syncthreads();
    for (int ks = 0; ks < 2; ++ks) {
      short8 af[4], bf[4];
      for (int i = 0; i < 4; ++i)
        af[i] = *(const short8*)(As + (wm + i * 16 + ln) * 64 + ks * 32 + q * 8);
      for (int j = 0; j < 4; ++j)
        bf[j] = *(const short8*)(Bs + (wn + j * 16 + ln) * 64 + ks * 32 + q * 8);
      for (int i = 0; i < 4; ++i)
        for (int j = 0; j < 4; ++j)
          acc[i][j] = MFMA16(af[i], bf[j], acc[i][j]);
    }
    __syncthreads();
  }
  for (int i = 0; i < 4; ++i) {
    long rowb = m0 + wm + i * 16 + q * 4;
    for (int j = 0; j < 4; ++j) {
      long col = n0 + wn + j * 16 + ln;
      float bv = bias[col];
      for (int r = 0; r < 4; ++r)
        Cf[(rowb + r) * (long)D_SZ + col] = acc[i][j][r] + bv;
    }
  }
}

// ---------------- flash attention ----------------
// 512-thr blocks (8 waves), 256-row q-tile, wave owns 32 q-rows.
// LDS double-buffered async K/V (XOR swizzle), one barrier per kv-tile,
// S^T trick, raw v_exp_f32, phase-split P (wave-private).
__global__ __launch_bounds__(512, 6) void attn_kernel(const unsigned short* __restrict__ Qb,
                                                      const unsigned short* __restrict__ Kb,
                                                      const unsigned short* __restrict__ Vt,
                                                      unsigned short* __restrict__ Ob) {
  // KV[buf][K 4096 | V 4096] shorts, swizzle: off(row,c8) = row*64 + ((c8 ^ (row&7))*8)
  __shared__ __align__(16) unsigned short KV[16384];   // 32768 B
  __shared__ __align__(16) unsigned short Pp[10240];   // 8 waves x 32 rows x pitch 40

  const int tid = threadIdx.x;
  const int wave = tid >> 6, lane = tid & 63;
  const int q = lane >> 4, ln = lane & 15;
  const int l7 = lane & 7, l3 = lane >> 3;
  const int qt = blockIdx.x, h = blockIdx.y, b = blockIdx.z;

  const long baseQ = ((long)b * T_SZ + qt * 256) * D_SZ + h * HD;
  const long baseK = (long)b * T_SZ * D_SZ + h * HD;
  const long baseV = (long)h * HD * M_SZ + (long)b * T_SZ;
  const int cs = ((l7 ^ l3) * 8);  // per-lane source column (shorts), matches swizzle

  short8 qf[2][2];
  for (int i = 0; i < 2; ++i)
    for (int ks = 0; ks < 2; ++ks)
      qf[i][ks] = *(const short8*)(Qb + baseQ + (long)(wave * 32 + i * 16 + ln) * D_SZ +
                                   ks * 32 + q * 8);

  float4v o[2][4] = {};
  float lp[2] = {};
  unsigned short* Ppw = Pp + wave * (32 * 40);
  const int swz = (ln & 7) * 8;  // frag-read swizzle term

// stage kv-tile kt_ into buffer base_: wave w stages K seg w and V seg w (1 KiB each)
#define STAGE(kt_, base_)                                                                \
  {                                                                                      \
    int row = wave * 8 + l3;                                                             \
    gl_lds16(Kb + baseK + (long)((kt_)*64 + row) * D_SZ + cs, (base_) + wave * 512);     \
    gl_lds16(Vt + baseV + (long)row * M_SZ + (kt_)*64 + cs, (base_) + 4096 + wave * 512);\
  }

  STAGE(0, KV)

  for (int kt = 0; kt < 32; ++kt) {
    unsigned short* cur = KV + (kt & 1) * 8192;
    unsigned short* nxt = KV + ((kt & 1) ^ 1) * 8192;
    __syncthreads();  // vmcnt drain: cur staged; prior readers of nxt done
    if (kt < 31) { STAGE(kt + 1, nxt) }  // async, lands during compute below

    // S^T = K Q'^T ; D: row = key (q*4+r), col = qrow (ln)
    short8 kf[4][2];
    for (int c = 0; c < 4; ++c)
      for (int ks = 0; ks < 2; ++ks)
        kf[c][ks] = *(const short8*)(cur + (c * 16 + ln) * 64 + ((ks * 32 + q * 8) ^ swz));
    float4v s[4][2];
    for (int c = 0; c < 4; ++c)
      for (int i = 0; i < 2; ++i) {
        float4v z = {};
        z = MFMA16(kf[c][0], qf[i][0], z);
        z = MFMA16(kf[c][1], qf[i][1], z);
        s[c][i] = z;
      }

    // two phases over key halves: exp2 -> Pp[qrow][key%32] -> PV MFMA
    for (int ks = 0; ks < 2; ++ks) {
      for (int i = 0; i < 2; ++i)
        for (int cl = 0; cl < 2; ++cl) {
          int c = 2 * ks + cl;
          float p0 = fexp2(s[c][i][0]);
          float p1 = fexp2(s[c][i][1]);
          float p2 = fexp2(s[c][i][2]);
          float p3 = fexp2(s[c][i][3]);
          lp[i] += (p0 + p1) + (p2 + p3);
          __hip_bfloat162 lo = __float22bfloat162_rn(make_float2(p0, p1));
          __hip_bfloat162 hi = __float22bfloat162_rn(make_float2(p2, p3));
          uint2 w;
          w.x = *(unsigned*)&lo;
          w.y = *(unsigned*)&hi;
          *(uint2*)(Ppw + (i * 16 + ln) * 40 + cl * 16 + q * 4) = w;
        }
      short8 vf[4];
      for (int j = 0; j < 4; ++j)
        vf[j] = *(const short8*)(cur + 4096 + (j * 16 + ln) * 64 + ((ks * 32 + q * 8) ^ swz));
      short8 pf[2];
      for (int i = 0; i < 2; ++i)
        pf[i] = *(const short8*)(Ppw + (i * 16 + ln) * 40 + q * 8);
      for (int i = 0; i < 2; ++i)
        for (int j = 0; j < 4; ++j)
          o[i][j] = MFMA16(pf[i], vf[j], o[i][j]);
    }
  }

  for (int i = 0; i < 2; ++i) {
    float l = lp[i];
    l += __shfl_xor(l, 16, 64);
    l += __shfl_xor(l, 32, 64);
    float inv = 1.f / l;  // lane holds qrow = i*16+ln
    for (int r = 0; r < 4; ++r) {
      int src = (lane & 48) | (q * 4 + r);
      float invr = __shfl(inv, src, 64);
      int row = qt * 256 + wave * 32 + i * 16 + q * 4 + r;
      long base = ((long)b * T_SZ + row) * D_SZ + h * HD;
      for (int j = 0; j < 4; ++j)
        Ob[base + j * 16 + ln] = f2bf(o[i][j][r] * invr);
    }
  }
#undef STAGE
}

extern "C" void kernel_launch(void* const* d_in, const int* in_sizes, int n_in,
                              void* d_out, int out_size, void* d_ws, size_t ws_size,
                              hipStream_t stream) {
  const float* x = (const float*)d_in[0];
  const float* Wq = (const float*)d_in[1];
  const float* bq = (const float*)d_in[2];
  const float* Wk = (const float*)d_in[3];
  const float* bk = (const float*)d_in[4];
  const float* Wv = (const float*)d_in[5];
  const float* bv = (const float*)d_in[6];
  const float* Wp = (const float*)d_in[7];
  const float* bp = (const float*)d_in[8];
  float* out = (float*)d_out;

  const long MX = (long)M_SZ * D_SZ;
  const long MW = (long)D_SZ * D_SZ;
  unsigned short* ws = (unsigned short*)d_ws;
  unsigned short* xb = ws;
  unsigned short* Wcat = xb + MX;
  float* bcat = (float*)(Wcat + 4 * MW);
  unsigned short* Qb = (unsigned short*)(bcat + 3072);
  unsigned short* Kb = Qb + MX;
  unsigned short* Vtb = Kb + MX;
  unsigned short* Ob = Vtb + MX;

  cvt_kernel<<<(int)(MX / 1024), 256, 0, stream>>>(x, xb, 1.0f, MX);
  cvt_w<<<(int)(4 * MW / 1024), 256, 0, stream>>>(Wq, Wk, Wv, Wp, Wcat, MW);
  cvt_bias<<<12, 256, 0, stream>>>(bq, bk, bv, bcat);

  dim3 gq(3072 / 128, M_SZ / 128);  // (24, 64)
  gemm_qkv<<<gq, 256, 0, stream>>>(xb, Wcat, bcat, Qb, Kb, Vtb);

  dim3 ag(T_SZ / 256, NH, B_SZ);  // (8, 16, 4) = 512 blocks of 512 threads
  attn_kernel<<<ag, 512, 0, stream>>>(Qb, Kb, Vtb, Ob);

  dim3 gp(D_SZ / 128, M_SZ / 128);  // (8, 64)
  gemm_proj<<<gp, 256, 0, stream>>>(Ob, Wcat + 3 * MW, bp, out);
}

// Round 7
// 277.949 us; speedup vs baseline: 3.4101x; 3.4101x over previous
//
#include <hip/hip_runtime.h>
#include <hip/hip_bf16.h>

// MHA: x[4,2048,1024] fp32, 16 heads x 64, no 1/sqrt(d) scale.
// cvt(x) + cvt(4 weights, Wq*log2e) + bias-concat -> fused QKV gemm (N=3072,
// V-blocks transposed in epilogue) -> flash attention (512-thr blocks, 256-row
// q-tiles, S^T trick, raw v_exp_f32, LDS-double-buffered async K/V staging,
// one barrier/iter; launch_bounds(512,4): cap 128 VGPR -- (512,6) forced 40
// and spilled 2.8 GB to scratch) -> proj gemm (fp32).

typedef short short8 __attribute__((ext_vector_type(8)));
typedef float float4v __attribute__((ext_vector_type(4)));

#define MFMA16(a, b, c) __builtin_amdgcn_mfma_f32_16x16x32_bf16((a), (b), (c), 0, 0, 0)
#define LOG2E 1.4426950408889634f

#define B_SZ 4
#define T_SZ 2048
#define D_SZ 1024
#define NH 16
#define HD 64
#define M_SZ (B_SZ * T_SZ)  // 8192

__device__ __forceinline__ unsigned short f2bf(float f) {
  unsigned int u = __float_as_uint(f);
  u += 0x7fffu + ((u >> 16) & 1u);
  return (unsigned short)(u >> 16);
}

__device__ __forceinline__ float fexp2(float x) {
#if __has_builtin(__builtin_amdgcn_exp2f)
  return __builtin_amdgcn_exp2f(x);  // bare v_exp_f32
#else
  return exp2f(x);
#endif
}

__device__ __forceinline__ void gl_lds16(const unsigned short* g, unsigned short* l) {
  __builtin_amdgcn_global_load_lds(
      (const __attribute__((address_space(1))) unsigned int*)g,
      (__attribute__((address_space(3))) unsigned int*)l, 16, 0, 0);
}

// ---------------- fp32 -> bf16 converts ----------------
__global__ __launch_bounds__(256) void cvt_kernel(const float* __restrict__ in,
                                                  unsigned short* __restrict__ out,
                                                  float scale, long n) {
  long i = ((long)blockIdx.x * 256 + threadIdx.x) * 4;
  if (i >= n) return;
  float4 v = *(const float4*)(in + i);
  uint2 o;
  o.x = (unsigned)f2bf(v.x * scale) | ((unsigned)f2bf(v.y * scale) << 16);
  o.y = (unsigned)f2bf(v.z * scale) | ((unsigned)f2bf(v.w * scale) << 16);
  *(uint2*)(out + i) = o;
}

__global__ __launch_bounds__(256) void cvt_w(const float* __restrict__ w0,
                                             const float* __restrict__ w1,
                                             const float* __restrict__ w2,
                                             const float* __restrict__ w3,
                                             unsigned short* __restrict__ out, long per) {
  long i = ((long)blockIdx.x * 256 + threadIdx.x) * 4;
  int which = (int)(i / per);
  const float* src = which == 0 ? w0 : which == 1 ? w1 : which == 2 ? w2 : w3;
  float scale = which == 0 ? LOG2E : 1.0f;
  long j = i - (long)which * per;
  float4 v = *(const float4*)(src + j);
  uint2 o;
  o.x = (unsigned)f2bf(v.x * scale) | ((unsigned)f2bf(v.y * scale) << 16);
  o.y = (unsigned)f2bf(v.z * scale) | ((unsigned)f2bf(v.w * scale) << 16);
  *(uint2*)(out + i) = o;
}

__global__ __launch_bounds__(256) void cvt_bias(const float* __restrict__ b0,
                                                const float* __restrict__ b1,
                                                const float* __restrict__ b2,
                                                float* __restrict__ out) {
  int i = blockIdx.x * 256 + threadIdx.x;  // 0..3071
  float v;
  if (i < 1024) v = b0[i] * LOG2E;
  else if (i < 2048) v = b1[i - 1024];
  else v = b2[i - 2048];
  out[i] = v;
}

// ---------------- fused QKV gemm: C[8192,3072] = x . [Wq;Wk;Wv]^T + b ----------------
__global__ __launch_bounds__(256, 2) void gemm_qkv(const unsigned short* __restrict__ A,
                                                   const unsigned short* __restrict__ W,
                                                   const float* __restrict__ bias,
                                                   unsigned short* __restrict__ Qb,
                                                   unsigned short* __restrict__ Kb,
                                                   unsigned short* __restrict__ Vt) {
  __shared__ __align__(16) unsigned short smem[17408];  // As|Bs / Ct (128x136)
  unsigned short* As = smem;
  unsigned short* Bs = smem + 8192;
  unsigned short* Ct = smem;
  const int tid = threadIdx.x;
  const int wave = tid >> 6, lane = tid & 63;
  const int q = lane >> 4, ln = lane & 15;
  const int wm = (wave >> 1) * 64, wn = (wave & 1) * 64;
  const long m0 = (long)blockIdx.y * 128;
  const long n0 = (long)blockIdx.x * 128;
  const int srow = lane >> 3, scol = (lane & 7) * 8;
  const int K = D_SZ;

  float4v acc[4][4] = {};

  for (int k0 = 0; k0 < K; k0 += 64) {
    for (int t = 0; t < 4; ++t) {
      int seg = wave * 4 + t;
      int row = seg * 8 + srow;
      gl_lds16(A + (m0 + row) * (long)K + k0 + scol, As + seg * 512);
      gl_lds16(W + (n0 + row) * (long)K + k0 + scol, Bs + seg * 512);
    }
    __syncthreads();
    for (int ks = 0; ks < 2; ++ks) {
      short8 af[4], bf[4];
      for (int i = 0; i < 4; ++i)
        af[i] = *(const short8*)(As + (wm + i * 16 + ln) * 64 + ks * 32 + q * 8);
      for (int j = 0; j < 4; ++j)
        bf[j] = *(const short8*)(Bs + (wn + j * 16 + ln) * 64 + ks * 32 + q * 8);
      for (int i = 0; i < 4; ++i)
        for (int j = 0; j < 4; ++j)
          acc[i][j] = MFMA16(af[i], bf[j], acc[i][j]);
    }
    __syncthreads();
  }

  if ((int)n0 < 2048) {
    unsigned short* dst = (int)n0 < 1024 ? Qb : Kb;
    int coff = (int)n0 < 1024 ? 0 : 1024;
    for (int i = 0; i < 4; ++i) {
      long rowb = m0 + wm + i * 16 + q * 4;
      for (int j = 0; j < 4; ++j) {
        long col = n0 + wn + j * 16 + ln;
        float bv = bias[col];
        for (int r = 0; r < 4; ++r)
          dst[(rowb + r) * (long)D_SZ + col - coff] = f2bf(acc[i][j][r] + bv);
      }
    }
  } else {
    for (int i = 0; i < 4; ++i)
      for (int j = 0; j < 4; ++j) {
        int col_l = wn + j * 16 + ln;
        float bv = bias[n0 + col_l];
        __hip_bfloat162 lo =
            __float22bfloat162_rn(make_float2(acc[i][j][0] + bv, acc[i][j][1] + bv));
        __hip_bfloat162 hi =
            __float22bfloat162_rn(make_float2(acc[i][j][2] + bv, acc[i][j][3] + bv));
        uint2 w;
        w.x = *(unsigned*)&lo;
        w.y = *(unsigned*)&hi;
        *(uint2*)(Ct + col_l * 136 + wm + i * 16 + q * 4) = w;
      }
    __syncthreads();
    for (int it = 0; it < 8; ++it) {
      int idx = tid + it * 256;
      int c = idx >> 4, rb = idx & 15;
      uint4 v = *(const uint4*)(Ct + c * 136 + rb * 8);
      *(uint4*)(Vt + (n0 - 2048 + c) * (long)M_SZ + m0 + rb * 8) = v;
    }
  }
}

// ---------------- proj gemm: out[8192,1024] = Ob . Wp^T + bp (fp32) ----------------
__global__ __launch_bounds__(256, 2) void gemm_proj(const unsigned short* __restrict__ A,
                                                    const unsigned short* __restrict__ W,
                                                    const float* __restrict__ bias,
                                                    float* __restrict__ Cf) {
  __shared__ __align__(16) unsigned short As[128 * 64];
  __shared__ __align__(16) unsigned short Bs[128 * 64];
  const int tid = threadIdx.x;
  const int wave = tid >> 6, lane = tid & 63;
  const int q = lane >> 4, ln = lane & 15;
  const int wm = (wave >> 1) * 64, wn = (wave & 1) * 64;
  const long m0 = (long)blockIdx.y * 128;
  const long n0 = (long)blockIdx.x * 128;
  const int srow = lane >> 3, scol = (lane & 7) * 8;
  const int K = D_SZ;

  float4v acc[4][4] = {};
  for (int k0 = 0; k0 < K; k0 += 64) {
    for (int t = 0; t < 4; ++t) {
      int seg = wave * 4 + t;
      int row = seg * 8 + srow;
      gl_lds16(A + (m0 + row) * (long)K + k0 + scol, As + seg * 512);
      gl_lds16(W + (n0 + row) * (long)K + k0 + scol, Bs + seg * 512);
    }
    __syncthreads();
    for (int ks = 0; ks < 2; ++ks) {
      short8 af[4], bf[4];
      for (int i = 0; i < 4; ++i)
        af[i] = *(const short8*)(As + (wm + i * 16 + ln) * 64 + ks * 32 + q * 8);
      for (int j = 0; j < 4; ++j)
        bf[j] = *(const short8*)(Bs + (wn + j * 16 + ln) * 64 + ks * 32 + q * 8);
      for (int i = 0; i < 4; ++i)
        for (int j = 0; j < 4; ++j)
          acc[i][j] = MFMA16(af[i], bf[j], acc[i][j]);
    }
    __syncthreads();
  }
  for (int i = 0; i < 4; ++i) {
    long rowb = m0 + wm + i * 16 + q * 4;
    for (int j = 0; j < 4; ++j) {
      long col = n0 + wn + j * 16 + ln;
      float bv = bias[col];
      for (int r = 0; r < 4; ++r)
        Cf[(rowb + r) * (long)D_SZ + col] = acc[i][j][r] + bv;
    }
  }
}

// ---------------- flash attention ----------------
// 512-thr blocks (8 waves), 256-row q-tile, wave owns 32 q-rows.
// LDS double-buffered async K/V (XOR swizzle), one barrier per kv-tile,
// S^T trick, raw v_exp_f32, phase-split P (wave-private).
// launch_bounds(512,4): VGPR cap 128 (kernel needs ~70-80; bound 6 forced 40 -> spill).
__global__ __launch_bounds__(512, 4) void attn_kernel(const unsigned short* __restrict__ Qb,
                                                      const unsigned short* __restrict__ Kb,
                                                      const unsigned short* __restrict__ Vt,
                                                      unsigned short* __restrict__ Ob) {
  // KV[buf][K 4096 | V 4096] shorts, swizzle: off(row,c8) = row*64 + ((c8 ^ (row&7))*8)
  __shared__ __align__(16) unsigned short KV[16384];   // 32768 B
  __shared__ __align__(16) unsigned short Pp[10240];   // 8 waves x 32 rows x pitch 40

  const int tid = threadIdx.x;
  const int wave = tid >> 6, lane = tid & 63;
  const int q = lane >> 4, ln = lane & 15;
  const int l7 = lane & 7, l3 = lane >> 3;
  const int qt = blockIdx.x, h = blockIdx.y, b = blockIdx.z;

  const long baseQ = ((long)b * T_SZ + qt * 256) * D_SZ + h * HD;
  const long baseK = (long)b * T_SZ * D_SZ + h * HD;
  const long baseV = (long)h * HD * M_SZ + (long)b * T_SZ;
  const int cs = ((l7 ^ l3) * 8);  // per-lane source column (shorts), matches swizzle

  short8 qf[2][2];
  for (int i = 0; i < 2; ++i)
    for (int ks = 0; ks < 2; ++ks)
      qf[i][ks] = *(const short8*)(Qb + baseQ + (long)(wave * 32 + i * 16 + ln) * D_SZ +
                                   ks * 32 + q * 8);

  float4v o[2][4] = {};
  float lp[2] = {};
  unsigned short* Ppw = Pp + wave * (32 * 40);
  const int swz = (ln & 7) * 8;  // frag-read swizzle term

// stage kv-tile kt_ into buffer base_: wave w stages K seg w and V seg w (1 KiB each)
#define STAGE(kt_, base_)                                                                \
  {                                                                                      \
    int row = wave * 8 + l3;                                                             \
    gl_lds16(Kb + baseK + (long)((kt_)*64 + row) * D_SZ + cs, (base_) + wave * 512);     \
    gl_lds16(Vt + baseV + (long)row * M_SZ + (kt_)*64 + cs, (base_) + 4096 + wave * 512);\
  }

  STAGE(0, KV)

  for (int kt = 0; kt < 32; ++kt) {
    unsigned short* cur = KV + (kt & 1) * 8192;
    unsigned short* nxt = KV + ((kt & 1) ^ 1) * 8192;
    __syncthreads();  // vmcnt drain: cur staged; prior readers of nxt done
    if (kt < 31) { STAGE(kt + 1, nxt) }  // async, lands during compute below

    // S^T = K Q'^T ; D: row = key (q*4+r), col = qrow (ln)
    short8 kf[4][2];
    for (int c = 0; c < 4; ++c)
      for (int ks = 0; ks < 2; ++ks)
        kf[c][ks] = *(const short8*)(cur + (c * 16 + ln) * 64 + ((ks * 32 + q * 8) ^ swz));
    float4v s[4][2];
    for (int c = 0; c < 4; ++c)
      for (int i = 0; i < 2; ++i) {
        float4v z = {};
        z = MFMA16(kf[c][0], qf[i][0], z);
        z = MFMA16(kf[c][1], qf[i][1], z);
        s[c][i] = z;
      }

    // two phases over key halves: exp2 -> Pp[qrow][key%32] -> PV MFMA
    for (int ks = 0; ks < 2; ++ks) {
      for (int i = 0; i < 2; ++i)
        for (int cl = 0; cl < 2; ++cl) {
          int c = 2 * ks + cl;
          float p0 = fexp2(s[c][i][0]);
          float p1 = fexp2(s[c][i][1]);
          float p2 = fexp2(s[c][i][2]);
          float p3 = fexp2(s[c][i][3]);
          lp[i] += (p0 + p1) + (p2 + p3);
          __hip_bfloat162 lo = __float22bfloat162_rn(make_float2(p0, p1));
          __hip_bfloat162 hi = __float22bfloat162_rn(make_float2(p2, p3));
          uint2 w;
          w.x = *(unsigned*)&lo;
          w.y = *(unsigned*)&hi;
          *(uint2*)(Ppw + (i * 16 + ln) * 40 + cl * 16 + q * 4) = w;
        }
      short8 vf[4];
      for (int j = 0; j < 4; ++j)
        vf[j] = *(const short8*)(cur + 4096 + (j * 16 + ln) * 64 + ((ks * 32 + q * 8) ^ swz));
      short8 pf[2];
      for (int i = 0; i < 2; ++i)
        pf[i] = *(const short8*)(Ppw + (i * 16 + ln) * 40 + q * 8);
      for (int i = 0; i < 2; ++i)
        for (int j = 0; j < 4; ++j)
          o[i][j] = MFMA16(pf[i], vf[j], o[i][j]);
    }
  }

  for (int i = 0; i < 2; ++i) {
    float l = lp[i];
    l += __shfl_xor(l, 16, 64);
    l += __shfl_xor(l, 32, 64);
    float inv = 1.f / l;  // lane holds qrow = i*16+ln
    for (int r = 0; r < 4; ++r) {
      int src = (lane & 48) | (q * 4 + r);
      float invr = __shfl(inv, src, 64);
      int row = qt * 256 + wave * 32 + i * 16 + q * 4 + r;
      long base = ((long)b * T_SZ + row) * D_SZ + h * HD;
      for (int j = 0; j < 4; ++j)
        Ob[base + j * 16 + ln] = f2bf(o[i][j][r] * invr);
    }
  }
#undef STAGE
}

extern "C" void kernel_launch(void* const* d_in, const int* in_sizes, int n_in,
                              void* d_out, int out_size, void* d_ws, size_t ws_size,
                              hipStream_t stream) {
  const float* x = (const float*)d_in[0];
  const float* Wq = (const float*)d_in[1];
  const float* bq = (const float*)d_in[2];
  const float* Wk = (const float*)d_in[3];
  const float* bk = (const float*)d_in[4];
  const float* Wv = (const float*)d_in[5];
  const float* bv = (const float*)d_in[6];
  const float* Wp = (const float*)d_in[7];
  const float* bp = (const float*)d_in[8];
  float* out = (float*)d_out;

  const long MX = (long)M_SZ * D_SZ;
  const long MW = (long)D_SZ * D_SZ;
  unsigned short* ws = (unsigned short*)d_ws;
  unsigned short* xb = ws;
  unsigned short* Wcat = xb + MX;
  float* bcat = (float*)(Wcat + 4 * MW);
  unsigned short* Qb = (unsigned short*)(bcat + 3072);
  unsigned short* Kb = Qb + MX;
  unsigned short* Vtb = Kb + MX;
  unsigned short* Ob = Vtb + MX;

  cvt_kernel<<<(int)(MX / 1024), 256, 0, stream>>>(x, xb, 1.0f, MX);
  cvt_w<<<(int)(4 * MW / 1024), 256, 0, stream>>>(Wq, Wk, Wv, Wp, Wcat, MW);
  cvt_bias<<<12, 256, 0, stream>>>(bq, bk, bv, bcat);

  dim3 gq(3072 / 128, M_SZ / 128);  // (24, 64)
  gemm_qkv<<<gq, 256, 0, stream>>>(xb, Wcat, bcat, Qb, Kb, Vtb);

  dim3 ag(T_SZ / 256, NH, B_SZ);  // (8, 16, 4) = 512 blocks of 512 threads
  attn_kernel<<<ag, 512, 0, stream>>>(Qb, Kb, Vtb, Ob);

  dim3 gp(D_SZ / 128, M_SZ / 128);  // (8, 64)
  gemm_proj<<<gp, 256, 0, stream>>>(Ob, Wcat + 3 * MW, bp, out);
}

// Round 8
// 277.553 us; speedup vs baseline: 3.4150x; 1.0014x over previous
//
#include <hip/hip_runtime.h>
#include <hip/hip_bf16.h>

// MHA: x[4,2048,1024] fp32, 16 heads x 64, no 1/sqrt(d) scale.
// cvt(x) + cvt(4 weights, Wq*log2e) + bias-concat -> fused QKV gemm (N=3072,
// V-blocks transposed in epilogue) -> flash attention (512-thr blocks, 256-row
// q-tiles, S^T trick, raw v_exp_f32, LDS-double-buffered async K/V staging,
// one barrier/iter) -> proj gemm (fp32).
// R8: GEMMs __launch_bounds__(256,3) -- cap 170 VGPR so 3 blocks/CU can be
// resident (LDS 34.8KB allows it; (256,2) allowed up to 256 VGPR -> possible
// 2-block cap). Attention unchanged from R7 (90 us, multi-pipe-contended).

typedef short short8 __attribute__((ext_vector_type(8)));
typedef float float4v __attribute__((ext_vector_type(4)));

#define MFMA16(a, b, c) __builtin_amdgcn_mfma_f32_16x16x32_bf16((a), (b), (c), 0, 0, 0)
#define LOG2E 1.4426950408889634f

#define B_SZ 4
#define T_SZ 2048
#define D_SZ 1024
#define NH 16
#define HD 64
#define M_SZ (B_SZ * T_SZ)  // 8192

__device__ __forceinline__ unsigned short f2bf(float f) {
  unsigned int u = __float_as_uint(f);
  u += 0x7fffu + ((u >> 16) & 1u);
  return (unsigned short)(u >> 16);
}

__device__ __forceinline__ float fexp2(float x) {
#if __has_builtin(__builtin_amdgcn_exp2f)
  return __builtin_amdgcn_exp2f(x);  // bare v_exp_f32
#else
  return exp2f(x);
#endif
}

__device__ __forceinline__ void gl_lds16(const unsigned short* g, unsigned short* l) {
  __builtin_amdgcn_global_load_lds(
      (const __attribute__((address_space(1))) unsigned int*)g,
      (__attribute__((address_space(3))) unsigned int*)l, 16, 0, 0);
}

// ---------------- fp32 -> bf16 converts ----------------
__global__ __launch_bounds__(256) void cvt_kernel(const float* __restrict__ in,
                                                  unsigned short* __restrict__ out,
                                                  float scale, long n) {
  long i = ((long)blockIdx.x * 256 + threadIdx.x) * 4;
  if (i >= n) return;
  float4 v = *(const float4*)(in + i);
  uint2 o;
  o.x = (unsigned)f2bf(v.x * scale) | ((unsigned)f2bf(v.y * scale) << 16);
  o.y = (unsigned)f2bf(v.z * scale) | ((unsigned)f2bf(v.w * scale) << 16);
  *(uint2*)(out + i) = o;
}

__global__ __launch_bounds__(256) void cvt_w(const float* __restrict__ w0,
                                             const float* __restrict__ w1,
                                             const float* __restrict__ w2,
                                             const float* __restrict__ w3,
                                             unsigned short* __restrict__ out, long per) {
  long i = ((long)blockIdx.x * 256 + threadIdx.x) * 4;
  int which = (int)(i / per);
  const float* src = which == 0 ? w0 : which == 1 ? w1 : which == 2 ? w2 : w3;
  float scale = which == 0 ? LOG2E : 1.0f;
  long j = i - (long)which * per;
  float4 v = *(const float4*)(src + j);
  uint2 o;
  o.x = (unsigned)f2bf(v.x * scale) | ((unsigned)f2bf(v.y * scale) << 16);
  o.y = (unsigned)f2bf(v.z * scale) | ((unsigned)f2bf(v.w * scale) << 16);
  *(uint2*)(out + i) = o;
}

__global__ __launch_bounds__(256) void cvt_bias(const float* __restrict__ b0,
                                                const float* __restrict__ b1,
                                                const float* __restrict__ b2,
                                                float* __restrict__ out) {
  int i = blockIdx.x * 256 + threadIdx.x;  // 0..3071
  float v;
  if (i < 1024) v = b0[i] * LOG2E;
  else if (i < 2048) v = b1[i - 1024];
  else v = b2[i - 2048];
  out[i] = v;
}

// ---------------- fused QKV gemm: C[8192,3072] = x . [Wq;Wk;Wv]^T + b ----------------
__global__ __launch_bounds__(256, 3) void gemm_qkv(const unsigned short* __restrict__ A,
                                                   const unsigned short* __restrict__ W,
                                                   const float* __restrict__ bias,
                                                   unsigned short* __restrict__ Qb,
                                                   unsigned short* __restrict__ Kb,
                                                   unsigned short* __restrict__ Vt) {
  __shared__ __align__(16) unsigned short smem[17408];  // As|Bs / Ct (128x136)
  unsigned short* As = smem;
  unsigned short* Bs = smem + 8192;
  unsigned short* Ct = smem;
  const int tid = threadIdx.x;
  const int wave = tid >> 6, lane = tid & 63;
  const int q = lane >> 4, ln = lane & 15;
  const int wm = (wave >> 1) * 64, wn = (wave & 1) * 64;
  const long m0 = (long)blockIdx.y * 128;
  const long n0 = (long)blockIdx.x * 128;
  const int srow = lane >> 3, scol = (lane & 7) * 8;
  const int K = D_SZ;

  float4v acc[4][4] = {};

  for (int k0 = 0; k0 < K; k0 += 64) {
    for (int t = 0; t < 4; ++t) {
      int seg = wave * 4 + t;
      int row = seg * 8 + srow;
      gl_lds16(A + (m0 + row) * (long)K + k0 + scol, As + seg * 512);
      gl_lds16(W + (n0 + row) * (long)K + k0 + scol, Bs + seg * 512);
    }
    __syncthreads();
    for (int ks = 0; ks < 2; ++ks) {
      short8 af[4], bf[4];
      for (int i = 0; i < 4; ++i)
        af[i] = *(const short8*)(As + (wm + i * 16 + ln) * 64 + ks * 32 + q * 8);
      for (int j = 0; j < 4; ++j)
        bf[j] = *(const short8*)(Bs + (wn + j * 16 + ln) * 64 + ks * 32 + q * 8);
      for (int i = 0; i < 4; ++i)
        for (int j = 0; j < 4; ++j)
          acc[i][j] = MFMA16(af[i], bf[j], acc[i][j]);
    }
    __syncthreads();
  }

  if ((int)n0 < 2048) {
    unsigned short* dst = (int)n0 < 1024 ? Qb : Kb;
    int coff = (int)n0 < 1024 ? 0 : 1024;
    for (int i = 0; i < 4; ++i) {
      long rowb = m0 + wm + i * 16 + q * 4;
      for (int j = 0; j < 4; ++j) {
        long col = n0 + wn + j * 16 + ln;
        float bv = bias[col];
        for (int r = 0; r < 4; ++r)
          dst[(rowb + r) * (long)D_SZ + col - coff] = f2bf(acc[i][j][r] + bv);
      }
    }
  } else {
    for (int i = 0; i < 4; ++i)
      for (int j = 0; j < 4; ++j) {
        int col_l = wn + j * 16 + ln;
        float bv = bias[n0 + col_l];
        __hip_bfloat162 lo =
            __float22bfloat162_rn(make_float2(acc[i][j][0] + bv, acc[i][j][1] + bv));
        __hip_bfloat162 hi =
            __float22bfloat162_rn(make_float2(acc[i][j][2] + bv, acc[i][j][3] + bv));
        uint2 w;
        w.x = *(unsigned*)&lo;
        w.y = *(unsigned*)&hi;
        *(uint2*)(Ct + col_l * 136 + wm + i * 16 + q * 4) = w;
      }
    __syncthreads();
    for (int it = 0; it < 8; ++it) {
      int idx = tid + it * 256;
      int c = idx >> 4, rb = idx & 15;
      uint4 v = *(const uint4*)(Ct + c * 136 + rb * 8);
      *(uint4*)(Vt + (n0 - 2048 + c) * (long)M_SZ + m0 + rb * 8) = v;
    }
  }
}

// ---------------- proj gemm: out[8192,1024] = Ob . Wp^T + bp (fp32) ----------------
__global__ __launch_bounds__(256, 3) void gemm_proj(const unsigned short* __restrict__ A,
                                                    const unsigned short* __restrict__ W,
                                                    const float* __restrict__ bias,
                                                    float* __restrict__ Cf) {
  __shared__ __align__(16) unsigned short As[128 * 64];
  __shared__ __align__(16) unsigned short Bs[128 * 64];
  const int tid = threadIdx.x;
  const int wave = tid >> 6, lane = tid & 63;
  const int q = lane >> 4, ln = lane & 15;
  const int wm = (wave >> 1) * 64, wn = (wave & 1) * 64;
  const long m0 = (long)blockIdx.y * 128;
  const long n0 = (long)blockIdx.x * 128;
  const int srow = lane >> 3, scol = (lane & 7) * 8;
  const int K = D_SZ;

  float4v acc[4][4] = {};
  for (int k0 = 0; k0 < K; k0 += 64) {
    for (int t = 0; t < 4; ++t) {
      int seg = wave * 4 + t;
      int row = seg * 8 + srow;
      gl_lds16(A + (m0 + row) * (long)K + k0 + scol, As + seg * 512);
      gl_lds16(W + (n0 + row) * (long)K + k0 + scol, Bs + seg * 512);
    }
    __syncthreads();
    for (int ks = 0; ks < 2; ++ks) {
      short8 af[4], bf[4];
      for (int i = 0; i < 4; ++i)
        af[i] = *(const short8*)(As + (wm + i * 16 + ln) * 64 + ks * 32 + q * 8);
      for (int j = 0; j < 4; ++j)
        bf[j] = *(const short8*)(Bs + (wn + j * 16 + ln) * 64 + ks * 32 + q * 8);
      for (int i = 0; i < 4; ++i)
        for (int j = 0; j < 4; ++j)
          acc[i][j] = MFMA16(af[i], bf[j], acc[i][j]);
    }
    __syncthreads();
  }
  for (int i = 0; i < 4; ++i) {
    long rowb = m0 + wm + i * 16 + q * 4;
    for (int j = 0; j < 4; ++j) {
      long col = n0 + wn + j * 16 + ln;
      float bv = bias[col];
      for (int r = 0; r < 4; ++r)
        Cf[(rowb + r) * (long)D_SZ + col] = acc[i][j][r] + bv;
    }
  }
}

// ---------------- flash attention (unchanged from R7: 90 us) ----------------
__global__ __launch_bounds__(512, 4) void attn_kernel(const unsigned short* __restrict__ Qb,
                                                      const unsigned short* __restrict__ Kb,
                                                      const unsigned short* __restrict__ Vt,
                                                      unsigned short* __restrict__ Ob) {
  // KV[buf][K 4096 | V 4096] shorts, swizzle: off(row,c8) = row*64 + ((c8 ^ (row&7))*8)
  __shared__ __align__(16) unsigned short KV[16384];   // 32768 B
  __shared__ __align__(16) unsigned short Pp[10240];   // 8 waves x 32 rows x pitch 40

  const int tid = threadIdx.x;
  const int wave = tid >> 6, lane = tid & 63;
  const int q = lane >> 4, ln = lane & 15;
  const int l7 = lane & 7, l3 = lane >> 3;
  const int qt = blockIdx.x, h = blockIdx.y, b = blockIdx.z;

  const long baseQ = ((long)b * T_SZ + qt * 256) * D_SZ + h * HD;
  const long baseK = (long)b * T_SZ * D_SZ + h * HD;
  const long baseV = (long)h * HD * M_SZ + (long)b * T_SZ;
  const int cs = ((l7 ^ l3) * 8);  // per-lane source column (shorts), matches swizzle

  short8 qf[2][2];
  for (int i = 0; i < 2; ++i)
    for (int ks = 0; ks < 2; ++ks)
      qf[i][ks] = *(const short8*)(Qb + baseQ + (long)(wave * 32 + i * 16 + ln) * D_SZ +
                                   ks * 32 + q * 8);

  float4v o[2][4] = {};
  float lp[2] = {};
  unsigned short* Ppw = Pp + wave * (32 * 40);
  const int swz = (ln & 7) * 8;  // frag-read swizzle term

// stage kv-tile kt_ into buffer base_: wave w stages K seg w and V seg w (1 KiB each)
#define STAGE(kt_, base_)                                                                \
  {                                                                                      \
    int row = wave * 8 + l3;                                                             \
    gl_lds16(Kb + baseK + (long)((kt_)*64 + row) * D_SZ + cs, (base_) + wave * 512);     \
    gl_lds16(Vt + baseV + (long)row * M_SZ + (kt_)*64 + cs, (base_) + 4096 + wave * 512);\
  }

  STAGE(0, KV)

  for (int kt = 0; kt < 32; ++kt) {
    unsigned short* cur = KV + (kt & 1) * 8192;
    unsigned short* nxt = KV + ((kt & 1) ^ 1) * 8192;
    __syncthreads();  // vmcnt drain: cur staged; prior readers of nxt done
    if (kt < 31) { STAGE(kt + 1, nxt) }  // async, lands during compute below

    // S^T = K Q'^T ; D: row = key (q*4+r), col = qrow (ln)
    short8 kf[4][2];
    for (int c = 0; c < 4; ++c)
      for (int ks = 0; ks < 2; ++ks)
        kf[c][ks] = *(const short8*)(cur + (c * 16 + ln) * 64 + ((ks * 32 + q * 8) ^ swz));
    float4v s[4][2];
    for (int c = 0; c < 4; ++c)
      for (int i = 0; i < 2; ++i) {
        float4v z = {};
        z = MFMA16(kf[c][0], qf[i][0], z);
        z = MFMA16(kf[c][1], qf[i][1], z);
        s[c][i] = z;
      }

    // two phases over key halves: exp2 -> Pp[qrow][key%32] -> PV MFMA
    for (int ks = 0; ks < 2; ++ks) {
      for (int i = 0; i < 2; ++i)
        for (int cl = 0; cl < 2; ++cl) {
          int c = 2 * ks + cl;
          float p0 = fexp2(s[c][i][0]);
          float p1 = fexp2(s[c][i][1]);
          float p2 = fexp2(s[c][i][2]);
          float p3 = fexp2(s[c][i][3]);
          lp[i] += (p0 + p1) + (p2 + p3);
          __hip_bfloat162 lo = __float22bfloat162_rn(make_float2(p0, p1));
          __hip_bfloat162 hi = __float22bfloat162_rn(make_float2(p2, p3));
          uint2 w;
          w.x = *(unsigned*)&lo;
          w.y = *(unsigned*)&hi;
          *(uint2*)(Ppw + (i * 16 + ln) * 40 + cl * 16 + q * 4) = w;
        }
      short8 vf[4];
      for (int j = 0; j < 4; ++j)
        vf[j] = *(const short8*)(cur + 4096 + (j * 16 + ln) * 64 + ((ks * 32 + q * 8) ^ swz));
      short8 pf[2];
      for (int i = 0; i < 2; ++i)
        pf[i] = *(const short8*)(Ppw + (i * 16 + ln) * 40 + q * 8);
      for (int i = 0; i < 2; ++i)
        for (int j = 0; j < 4; ++j)
          o[i][j] = MFMA16(pf[i], vf[j], o[i][j]);
    }
  }

  for (int i = 0; i < 2; ++i) {
    float l = lp[i];
    l += __shfl_xor(l, 16, 64);
    l += __shfl_xor(l, 32, 64);
    float inv = 1.f / l;  // lane holds qrow = i*16+ln
    for (int r = 0; r < 4; ++r) {
      int src = (lane & 48) | (q * 4 + r);
      float invr = __shfl(inv, src, 64);
      int row = qt * 256 + wave * 32 + i * 16 + q * 4 + r;
      long base = ((long)b * T_SZ + row) * D_SZ + h * HD;
      for (int j = 0; j < 4; ++j)
        Ob[base + j * 16 + ln] = f2bf(o[i][j][r] * invr);
    }
  }
#undef STAGE
}

extern "C" void kernel_launch(void* const* d_in, const int* in_sizes, int n_in,
                              void* d_out, int out_size, void* d_ws, size_t ws_size,
                              hipStream_t stream) {
  const float* x = (const float*)d_in[0];
  const float* Wq = (const float*)d_in[1];
  const float* bq = (const float*)d_in[2];
  const float* Wk = (const float*)d_in[3];
  const float* bk = (const float*)d_in[4];
  const float* Wv = (const float*)d_in[5];
  const float* bv = (const float*)d_in[6];
  const float* Wp = (const float*)d_in[7];
  const float* bp = (const float*)d_in[8];
  float* out = (float*)d_out;

  const long MX = (long)M_SZ * D_SZ;
  const long MW = (long)D_SZ * D_SZ;
  unsigned short* ws = (unsigned short*)d_ws;
  unsigned short* xb = ws;
  unsigned short* Wcat = xb + MX;
  float* bcat = (float*)(Wcat + 4 * MW);
  unsigned short* Qb = (unsigned short*)(bcat + 3072);
  unsigned short* Kb = Qb + MX;
  unsigned short* Vtb = Kb + MX;
  unsigned short* Ob = Vtb + MX;

  cvt_kernel<<<(int)(MX / 1024), 256, 0, stream>>>(x, xb, 1.0f, MX);
  cvt_w<<<(int)(4 * MW / 1024), 256, 0, stream>>>(Wq, Wk, Wv, Wp, Wcat, MW);
  cvt_bias<<<12, 256, 0, stream>>>(bq, bk, bv, bcat);

  dim3 gq(3072 / 128, M_SZ / 128);  // (24, 64)
  gemm_qkv<<<gq, 256, 0, stream>>>(xb, Wcat, bcat, Qb, Kb, Vtb);

  dim3 ag(T_SZ / 256, NH, B_SZ);  // (8, 16, 4) = 512 blocks of 512 threads
  attn_kernel<<<ag, 512, 0, stream>>>(Qb, Kb, Vtb, Ob);

  dim3 gp(D_SZ / 128, M_SZ / 128);  // (8, 64)
  gemm_proj<<<gp, 256, 0, stream>>>(Ob, Wcat + 3 * MW, bp, out);
}